// Round 5
// baseline (118.468 us; speedup 1.0000x reference)
//
#include <hip/hip_runtime.h>

#define TPB 256
#define QW  16      // queries per block (held in per-thread regs, wave-uniform)
#define NW  4       // waves per block; each wave covers 1/NW of the database

typedef float f2 __attribute__((ext_vector_type(2)));

// One distance-pair vs the QW uniform queries.
// Expression text identical to all prior verified kernels:
//   n   = x*x + y*y + z*z
//   s   = ax*(-2x) + (ay*(-2y) + (az*(-2z) + n))
//   min-fold via fminf(fminf(...)) -> v_min3_f32
#define DOPAIR(X0, Y0, Z0, X1, Y1, Z1)                                  \
    do {                                                                \
        float n0 = (X0) * (X0) + (Y0) * (Y0) + (Z0) * (Z0);             \
        float n1 = (X1) * (X1) + (Y1) * (Y1) + (Z1) * (Z1);             \
        f2 xx = {-2.0f * (X0), -2.0f * (X1)};                           \
        f2 yy = {-2.0f * (Y0), -2.0f * (Y1)};                           \
        f2 zz = {-2.0f * (Z0), -2.0f * (Z1)};                           \
        f2 ww = {n0, n1};                                               \
        _Pragma("unroll")                                               \
        for (int k = 0; k < QW; k++) {                                  \
            f2 sv = zz * qz[k] + ww;                                    \
            sv    = yy * qy[k] + sv;                                    \
            sv    = xx * qx[k] + sv;                                    \
            vmn[k] = fminf(fminf(vmn[k], sv[0]), sv[1]);                \
        }                                                               \
    } while (0)

// One unit = 4 db points = 12 floats = 3 aligned float4 loads.
#define DOUNIT(a, b2, c)                                                \
    do {                                                                \
        DOPAIR((a).x, (a).y, (a).z, (a).w, (b2).x, (b2).y);             \
        DOPAIR((b2).z, (b2).w, (c).x, (c).y, (c).z, (c).w);             \
    } while (0)

#define LDU(a, b2, c, t_)                                               \
    do {                                                                \
        int u_ = ubase + (t_) * 64 + lane;                              \
        u_ = u_ < NU ? u_ : NU - 1;          /* dup unit: min-safe */   \
        int fb_ = 12 * u_;                                              \
        fb_ = fb_ < fbmax ? fb_ : fbmax;     /* 12-float window fits */ \
        const float4* p4_ = (const float4*)(dbase + fb_);               \
        a = p4_[0]; b2 = p4_[1]; c = p4_[2];                            \
    } while (0)

__global__ __launch_bounds__(TPB, 4) void chamfer_nn(
        const float* __restrict__ pos, const float* __restrict__ xhat,
        int N, int M, float inv1, float inv2, float* __restrict__ out) {
    const int s   = blockIdx.y;              // stream = b*2 + dir
    const int dir = s & 1, b = s >> 1;
    // dir 0: queries = pos, db = xhat (dist1); dir 1: queries = xhat, db = pos
    const float* __restrict__ A  = dir ? xhat : pos;
    const float* __restrict__ Bp = dir ? pos  : xhat;
    const int NA = dir ? M : N;
    const int NB = dir ? N : M;
    const float invW = dir ? inv2 : inv1;

    const int wv   = threadIdx.x >> 6;
    const int lane = threadIdx.x & 63;

    __shared__ float cm[NW][QW];             // per-wave per-query min
    __shared__ float cavs[QW];               // |a|^2 per query

    // ---- queries: broadcast-load QW points into uniform VGPRs ----
    const float* qbase = A + (size_t)b * NA * 3;
    float qx[QW], qy[QW], qz[QW], vmn[QW];
#pragma unroll
    for (int k = 0; k < QW; k++) {
        int iq = blockIdx.x * QW + k;
        int ic = iq < NA ? iq : NA - 1;      // clamp; masked at contribution
        const float* p = qbase + (size_t)ic * 3;
        float x = p[0], y = p[1], z = p[2];
        qx[k] = x; qy[k] = y; qz[k] = z;
        if (threadIdx.x == 0) cavs[k] = x * x + y * y + z * z;
        vmn[k] = 3.4e38f;
    }

    // ---- this wave's share of the database ----
    const float* dbase = Bp + (size_t)b * NB * 3;
    const int NU    = (NB + 3) >> 2;         // 4-point units in db
    const int UPW   = (NU + NW - 1) / NW;    // units per wave
    const int ubase = wv * UPW;
    const int T     = (UPW + 63) >> 6;       // unit-iters per lane (8 here)
    const int fbmax = 3 * NB - 12;

    float4 Aa, Ab, Ac, Ba, Bb, Bc;
    LDU(Aa, Ab, Ac, 0);
    if (T >= 2) {
        LDU(Ba, Bb, Bc, 1);
        int t = 0;
        for (; t + 3 < T; t += 2) {          // depth-2 pipeline
            float4 Ca, Cb, Cc, Da, Db, Dc;
            LDU(Ca, Cb, Cc, t + 2);
            DOUNIT(Aa, Ab, Ac);
            LDU(Da, Db, Dc, t + 3);
            DOUNIT(Ba, Bb, Bc);
            Aa = Ca; Ab = Cb; Ac = Cc;
            Ba = Da; Bb = Db; Bc = Dc;
        }
        DOUNIT(Aa, Ab, Ac);
        DOUNIT(Ba, Bb, Bc);
        t += 2;
        if (t < T) { LDU(Aa, Ab, Ac, t); DOUNIT(Aa, Ab, Ac); }
    } else {
        DOUNIT(Aa, Ab, Ac);
    }

    // ---- per-wave lane butterfly, stash into LDS ----
#pragma unroll
    for (int k = 0; k < QW; k++) {
        float m = vmn[k];
        m = fminf(m, __shfl_xor(m, 1));
        m = fminf(m, __shfl_xor(m, 2));
        m = fminf(m, __shfl_xor(m, 4));
        m = fminf(m, __shfl_xor(m, 8));
        m = fminf(m, __shfl_xor(m, 16));
        m = fminf(m, __shfl_xor(m, 32));
        if (lane == 0) cm[wv][k] = m;
    }
    __syncthreads();

    // ---- cross-wave combine + weighted sum: threads 0..QW-1 of wave 0 ----
    float contrib = 0.0f;
    if (threadIdx.x < QW) {
        int k  = threadIdx.x;
        int iq = blockIdx.x * QW + k;
        if (iq < NA) {
            float m = fminf(fminf(cm[0][k], cm[1][k]),
                            fminf(cm[2][k], cm[3][k]));
            contrib = fmaxf(cavs[k] + m, 0.0f) * invW;
        }
    }
    if (wv == 0) {
        contrib += __shfl_xor(contrib, 1);
        contrib += __shfl_xor(contrib, 2);
        contrib += __shfl_xor(contrib, 4);
        contrib += __shfl_xor(contrib, 8);
        if (lane == 0) {
            atomicAdd(&out[0], contrib);     // loss
            atomicAdd(&out[1], contrib);     // rec_loss (identical)
        }
    }
}

extern "C" void kernel_launch(void* const* d_in, const int* in_sizes, int n_in,
                              void* d_out, int out_size, void* d_ws, size_t ws_size,
                              hipStream_t stream) {
    const float* pos  = (const float*)d_in[0];
    const float* xhat = (const float*)d_in[1];
    const int B = 2;
    const int N = in_sizes[0] / (B * 3);   // 8192
    const int M = in_sizes[1] / (B * 3);   // 8192
    float* out = (float*)d_out;
    (void)d_ws; (void)ws_size;             // workspace intentionally unused

    const int mxq = N > M ? N : M;
    const int QG  = (mxq + QW - 1) / QW;                   // 512 q-groups

    (void)hipMemsetAsync(out, 0, 2 * sizeof(float), stream);

    dim3 grid(QG, B * 2);                                  // 2048 blocks
    chamfer_nn<<<grid, TPB, 0, stream>>>(pos, xhat, N, M,
                                         1.0f / (B * N), 1.0f / (B * M), out);
}